// Round 16
// baseline (206.592 us; speedup 1.0000x reference)
//
#include <hip/hip_runtime.h>

// RNN scan: h_{t+1} = relu(W_hh @ h_t + x_t * w_x), out = W_hy @ h_T
// B=8192, T=512, H=64.
// Round 16 = zero-exchange permuted-tile (r14, verified) + TWO independent
// batch chains per wave + cheap pack.
//  - 2 chains P/Q (cols b0..b0+16 / b0+16..b0+32) share A-frags and wx;
//    their MFMA/pack streams interleave so each chain's latency hides under
//    the partner's issue (the only independent work available at 512 waves).
//    grid 256 x 64thr = 1 wave/CU, all CUs covered.
//  - pack: bias-add + shift + and-or TRUNCATION pack (4 VALU/pair,
//    round-half-up ~ RNE) + relu as v_pk_max_i16 via
//    __builtin_elementwise_max(short2) -- no inline asm (r13 lesson),
//    ~48 VALU/chain/step vs ~190 for the software-RNE (__bf16) cast path.
// Tiles: I_m[i] = 32*(m>>1) + 8*(i>>2) + 4*(m&1) + (i&3); lane (c,g)'s 16
// C slots are exactly its own next-step B-fragments (r14-verified).
// Layouts (r10/r14-verified): A row=lane&15, k=8*(lane>>4)+e;
//   B col=lane&15, k=8*(lane>>4)+e; C col=lane&15, row=4*(lane>>4)+reg.

typedef __bf16 bf16x8 __attribute__((ext_vector_type(8)));
typedef float f32x4 __attribute__((ext_vector_type(4)));
typedef unsigned int u32x4 __attribute__((ext_vector_type(4)));
typedef short s16x2 __attribute__((ext_vector_type(2)));

#define RNN_B 8192
#define RNN_T 512
#define RNN_H 64

// pack two f32 -> packed bf16 word (lo = a, hi = b), round-half-up, then relu
__device__ __forceinline__ unsigned pk_relu_rhu(float a, float b) {
  unsigned ua = __builtin_bit_cast(unsigned, a) + 0x8000u;
  unsigned ub = __builtin_bit_cast(unsigned, b) + 0x8000u;
  unsigned w  = (ub & 0xffff0000u) | (ua >> 16);
  s16x2 v = __builtin_bit_cast(s16x2, w);
  s16x2 z = {};
  v = __builtin_elementwise_max(v, z);       // v_pk_max_i16: relu on bf16 halves
  return __builtin_bit_cast(unsigned, v);
}

__global__ __launch_bounds__(64, 1) void rnn_scan_kernel(
    const float* __restrict__ x,
    const float* __restrict__ Wxh,
    const float* __restrict__ Whh,
    const float* __restrict__ Why,
    float* __restrict__ out)
{
  const int lane = threadIdx.x;
  const int c    = lane & 15;      // batch col within chain
  const int g    = lane >> 4;      // lane group
  const int b0   = blockIdx.x * 32;

  // ---- A frags: A[m][kh], lane (c,g) = W_hh[I_m[c]][32kh + 8g + e] ----
  bf16x8 A[4][2];
#pragma unroll
  for (int m = 0; m < 4; ++m) {
    const int row = 32 * (m >> 1) + 8 * (c >> 2) + 4 * (m & 1) + (c & 3);
#pragma unroll
    for (int kh = 0; kh < 2; ++kh) {
      const float* wp = Whh + (size_t)row * RNN_H + 32 * kh + 8 * g;
      float4 w0 = *(const float4*)(wp);
      float4 w1 = *(const float4*)(wp + 4);
      bf16x8 f;
      f[0] = (__bf16)w0.x; f[1] = (__bf16)w0.y; f[2] = (__bf16)w0.z; f[3] = (__bf16)w0.w;
      f[4] = (__bf16)w1.x; f[5] = (__bf16)w1.y; f[6] = (__bf16)w1.z; f[7] = (__bf16)w1.w;
      A[m][kh] = f;
    }
  }

  // ---- w_x per C slot: tile m reg r -> row I_m[4g+r] (shared) ----
  f32x4 wx0, wx1, wx2, wx3;
#pragma unroll
  for (int r = 0; r < 4; ++r) {
    wx0[r] = Wxh[8 * g + r];
    wx1[r] = Wxh[8 * g + 4 + r];
    wx2[r] = Wxh[32 + 8 * g + r];
    wx3[r] = Wxh[32 + 8 * g + 4 + r];
  }

  const float* xrP = x + (size_t)(b0 + c) * RNN_T;
  const float* xrQ = x + (size_t)(b0 + 16 + c) * RNN_T;
  float4 xp0 = *(const float4*)(xrP), xp1 = *(const float4*)(xrP + 4);
  float4 xq0 = *(const float4*)(xrQ), xq1 = *(const float4*)(xrQ + 4);

  f32x4 aP0 = {}, aP1 = {}, aP2 = {}, aP3 = {};
  f32x4 aQ0 = {}, aQ1 = {}, aQ2 = {}, aQ3 = {};
  u32x4 BP0 = {}, BP1 = {}, BQ0 = {}, BQ1 = {};   // B frags (h_0 = 0)

  for (int tb = 0; tb < RNN_T; tb += 8) {
    const int tn = (tb + 8 < RNN_T) ? tb + 8 : tb;
    float4 np0 = *(const float4*)(xrP + tn), np1 = *(const float4*)(xrP + tn + 4);
    float4 nq0 = *(const float4*)(xrQ + tn), nq1 = *(const float4*)(xrQ + tn + 4);
    const float xsP[8] = {xp0.x, xp0.y, xp0.z, xp0.w, xp1.x, xp1.y, xp1.z, xp1.w};
    const float xsQ[8] = {xq0.x, xq0.y, xq0.z, xq0.w, xq1.x, xq1.y, xq1.z, xq1.w};
#pragma unroll
    for (int j = 0; j < 8; ++j) {
      const float xvP = xsP[j], xvQ = xsQ[j];
      bf16x8 bP0 = __builtin_bit_cast(bf16x8, BP0);
      bf16x8 bP1 = __builtin_bit_cast(bf16x8, BP1);
      bf16x8 bQ0 = __builtin_bit_cast(bf16x8, BQ0);
      bf16x8 bQ1 = __builtin_bit_cast(bf16x8, BQ1);
      // k-half 0 (C-in = f32-exact x-term), P/Q interleaved
      aP0 = __builtin_amdgcn_mfma_f32_16x16x32_bf16(A[0][0], bP0, wx0 * xvP, 0, 0, 0);
      aQ0 = __builtin_amdgcn_mfma_f32_16x16x32_bf16(A[0][0], bQ0, wx0 * xvQ, 0, 0, 0);
      aP1 = __builtin_amdgcn_mfma_f32_16x16x32_bf16(A[1][0], bP0, wx1 * xvP, 0, 0, 0);
      aQ1 = __builtin_amdgcn_mfma_f32_16x16x32_bf16(A[1][0], bQ0, wx1 * xvQ, 0, 0, 0);
      aP2 = __builtin_amdgcn_mfma_f32_16x16x32_bf16(A[2][0], bP0, wx2 * xvP, 0, 0, 0);
      aQ2 = __builtin_amdgcn_mfma_f32_16x16x32_bf16(A[2][0], bQ0, wx2 * xvQ, 0, 0, 0);
      aP3 = __builtin_amdgcn_mfma_f32_16x16x32_bf16(A[3][0], bP0, wx3 * xvP, 0, 0, 0);
      aQ3 = __builtin_amdgcn_mfma_f32_16x16x32_bf16(A[3][0], bQ0, wx3 * xvQ, 0, 0, 0);
      // k-half 1 (chained)
      aP0 = __builtin_amdgcn_mfma_f32_16x16x32_bf16(A[0][1], bP1, aP0, 0, 0, 0);
      aQ0 = __builtin_amdgcn_mfma_f32_16x16x32_bf16(A[0][1], bQ1, aQ0, 0, 0, 0);
      aP1 = __builtin_amdgcn_mfma_f32_16x16x32_bf16(A[1][1], bP1, aP1, 0, 0, 0);
      aQ1 = __builtin_amdgcn_mfma_f32_16x16x32_bf16(A[1][1], bQ1, aQ1, 0, 0, 0);
      aP2 = __builtin_amdgcn_mfma_f32_16x16x32_bf16(A[2][1], bP1, aP2, 0, 0, 0);
      aQ2 = __builtin_amdgcn_mfma_f32_16x16x32_bf16(A[2][1], bQ1, aQ2, 0, 0, 0);
      aP3 = __builtin_amdgcn_mfma_f32_16x16x32_bf16(A[3][1], bP1, aP3, 0, 0, 0);
      aQ3 = __builtin_amdgcn_mfma_f32_16x16x32_bf16(A[3][1], bQ1, aQ3, 0, 0, 0);

      // pack in place: C slots ARE the next B frags (cheap trunc pack)
      BP0[0] = pk_relu_rhu(aP0[0], aP0[1]);
      BQ0[0] = pk_relu_rhu(aQ0[0], aQ0[1]);
      BP0[1] = pk_relu_rhu(aP0[2], aP0[3]);
      BQ0[1] = pk_relu_rhu(aQ0[2], aQ0[3]);
      BP0[2] = pk_relu_rhu(aP1[0], aP1[1]);
      BQ0[2] = pk_relu_rhu(aQ1[0], aQ1[1]);
      BP0[3] = pk_relu_rhu(aP1[2], aP1[3]);
      BQ0[3] = pk_relu_rhu(aQ1[2], aQ1[3]);
      BP1[0] = pk_relu_rhu(aP2[0], aP2[1]);
      BQ1[0] = pk_relu_rhu(aQ2[0], aQ2[1]);
      BP1[1] = pk_relu_rhu(aP2[2], aP2[3]);
      BQ1[1] = pk_relu_rhu(aQ2[2], aQ2[3]);
      BP1[2] = pk_relu_rhu(aP3[0], aP3[1]);
      BQ1[2] = pk_relu_rhu(aQ3[0], aQ3[1]);
      BP1[3] = pk_relu_rhu(aP3[2], aP3[3]);
      BQ1[3] = pk_relu_rhu(aQ3[2], aQ3[3]);
    }
    xp0 = np0; xp1 = np1; xq0 = nq0; xq1 = nq1;
  }

  // ---- epilogue: out[b] = sum_rows Why * relu(h_T), both chains ----
  float pw = 0.0f, qw = 0.0f;
#pragma unroll
  for (int r = 0; r < 4; ++r) {
    const float w0 = Why[8 * g + r];
    const float w1 = Why[8 * g + 4 + r];
    const float w2 = Why[32 + 8 * g + r];
    const float w3 = Why[32 + 8 * g + 4 + r];
    pw += w0 * fmaxf(aP0[r], 0.0f) + w1 * fmaxf(aP1[r], 0.0f)
        + w2 * fmaxf(aP2[r], 0.0f) + w3 * fmaxf(aP3[r], 0.0f);
    qw += w0 * fmaxf(aQ0[r], 0.0f) + w1 * fmaxf(aQ1[r], 0.0f)
        + w2 * fmaxf(aQ2[r], 0.0f) + w3 * fmaxf(aQ3[r], 0.0f);
  }
  pw += __shfl_xor(pw, 16, 64);
  pw += __shfl_xor(pw, 32, 64);
  qw += __shfl_xor(qw, 16, 64);
  qw += __shfl_xor(qw, 32, 64);
  if (lane < 16) {
    out[b0 + c]      = pw;
    out[b0 + 16 + c] = qw;
  }
}

extern "C" void kernel_launch(void* const* d_in, const int* in_sizes, int n_in,
                              void* d_out, int out_size, void* d_ws, size_t ws_size,
                              hipStream_t stream) {
  const float* x   = (const float*)d_in[0];
  const float* Wxh = (const float*)d_in[1];
  const float* Whh = (const float*)d_in[2];
  const float* Why = (const float*)d_in[3];
  float* out = (float*)d_out;
  (void)in_sizes; (void)n_in; (void)out_size; (void)d_ws; (void)ws_size;
  rnn_scan_kernel<<<dim3(RNN_B / 32), dim3(64), 0, stream>>>(x, Wxh, Whh, Why, out);
}

// Round 17
// 92.457 us; speedup vs baseline: 2.2345x; 2.2345x over previous
//
#include <hip/hip_runtime.h>

// RNN scan: h_{t+1} = relu(W_hh @ h_t + x_t * w_x), out = W_hy @ h_T
// B=8192, T=512, H=64.
// Round 17 = round 12 (best: 16x16x32 bf16, 4-wave M-split, lane-major
// exchange, 2 blocks/CU = 8 waves/CU) + K-SPLIT REASSOCIATION only:
//   was: acc = mfma(A1, Bv1, mfma(A0, Bv0, x*wx))   (2 chained latencies)
//   now: P = mfma(A0, Bv0, x*wx); Q = mfma(A1, Bv1, 0); acc = P + Q
//   -> both MFMAs independent, one latency on the recurrent path,
//      +2 v_pk_add_f32. Everything else byte-identical to r12.
// Throughput table (cols/cyc/CU): r12 M-split 0.074 > r14 zero-exch 0.053 >
// r16 1-wave ILP 0.033 -- only M-split fills all SIMDs (512 chains, 1024
// SIMDs). TLP > ILP > saved-exchange.
// Layouts: C (m89): col=lane&15, row=4*(lane>>4)+reg.
//   A/B (r10-verified): row/col=lane&15, k=8*(lane>>4)+e.
// Exchange: reader lane l's full B-frag at byte 16*l (conflict-free b128
// reads); writers scatter (2-way-free b64). Double-buffered, one
// {lgkmcnt(0); s_barrier} per step.

typedef __bf16 bf16x8 __attribute__((ext_vector_type(8)));
typedef float f32x4 __attribute__((ext_vector_type(4)));
typedef unsigned int u32x4 __attribute__((ext_vector_type(4)));
typedef unsigned int u32x2 __attribute__((ext_vector_type(2)));

#define RNN_B 8192
#define RNN_T 512
#define RNN_H 64

__global__ __launch_bounds__(256, 1) void rnn_scan_kernel(
    const float* __restrict__ x,
    const float* __restrict__ Wxh,
    const float* __restrict__ Whh,
    const float* __restrict__ Why,
    float* __restrict__ out)
{
  const int tid  = threadIdx.x;
  const int mu   = tid >> 6;       // wave: owns h rows [16mu, 16mu+16)
  const int lane = tid & 63;
  const int c    = lane & 15;      // batch col within block
  const int g    = lane >> 4;      // lane group (C rows 4g..4g+3, B k 8g..8g+7)
  const int b0   = blockIdx.x * 16;

  // [buf][khalf][reader lane]: reader lane l reads its 16B frag at 16*l
  __shared__ u32x4 xbuf[2][2][256];          // 16 KiB
  __shared__ float partial[4][16];

  // ---- A frags: W_hh[16mu + c][32k + 8g + e], k-halves k=0,1 ----
  bf16x8 A[2];
#pragma unroll
  for (int k = 0; k < 2; ++k) {
    const float* wp = Whh + (size_t)(16 * mu + c) * RNN_H + 32 * k + 8 * g;
    float4 w0 = *(const float4*)(wp);
    float4 w1 = *(const float4*)(wp + 4);
    bf16x8 f;
    f[0] = (__bf16)w0.x; f[1] = (__bf16)w0.y; f[2] = (__bf16)w0.z; f[3] = (__bf16)w0.w;
    f[4] = (__bf16)w1.x; f[5] = (__bf16)w1.y; f[6] = (__bf16)w1.z; f[7] = (__bf16)w1.w;
    A[k] = f;
  }

  // ---- w_x per C slot: row = 16mu + 4g + r ----
  f32x4 wxv;
#pragma unroll
  for (int r = 0; r < 4; ++r) wxv[r] = Wxh[16 * mu + 4 * g + r];

  // writer target: kh = mu>>1, reader lane rl, dword-pair offset 8*(g&1)
  const int kh = mu >> 1;
  const int rl = c + 32 * (mu & 1) + 16 * (g >> 1);

  const float* xrow = x + (size_t)(b0 + c) * RNN_T;
  float4 xc0 = *(const float4*)(xrow);
  float4 xc1 = *(const float4*)(xrow + 4);

  f32x4 zf4 = {};
  f32x4 acc = {};                  // own rows' pre-relu h (4 regs)
  u32x4 Bv0 = {}, Bv1 = {};        // B frags, k-halves (h_0 = 0)
  unsigned zero_u = 0;

  for (int tb = 0; tb < RNN_T; tb += 8) {
    const int tn = (tb + 8 < RNN_T) ? tb + 8 : tb;
    float4 xn0 = *(const float4*)(xrow + tn);
    float4 xn1 = *(const float4*)(xrow + tn + 4);
    const float xs[8] = {xc0.x, xc0.y, xc0.z, xc0.w, xc1.x, xc1.y, xc1.z, xc1.w};
#pragma unroll
    for (int j = 0; j < 8; ++j) {
      const float xv = xs[j];
      // k-split: two INDEPENDENT MFMAs (one latency on the recurrent path)
      f32x4 P = __builtin_amdgcn_mfma_f32_16x16x32_bf16(A[0], __builtin_bit_cast(bf16x8, Bv0), wxv * xv, 0, 0, 0);
      f32x4 Q = __builtin_amdgcn_mfma_f32_16x16x32_bf16(A[1], __builtin_bit_cast(bf16x8, Bv1), zf4,      0, 0, 0);
      f32x4 a = P + Q;             // v_pk_add_f32 x2
      acc = a;

      // pack own 4 rows (16mu+4g+0..3, col c): cvt_pk (RNE) + relu on packed
      unsigned w0, w1;
      asm("v_cvt_pk_bf16_f32 %0, %1, %2" : "=v"(w0) : "v"(a[0]), "v"(a[1]));
      asm("v_cvt_pk_bf16_f32 %0, %1, %2" : "=v"(w1) : "v"(a[2]), "v"(a[3]));
      asm("v_pk_max_i16 %0, %1, %2" : "=v"(w0) : "v"(w0), "v"(zero_u));
      asm("v_pk_max_i16 %0, %1, %2" : "=v"(w1) : "v"(w1), "v"(zero_u));

      // scatter-write into reader lane rl's frag word (dwords 2(g&1)..+1)
      const int q = (j + 1) & 1;               // parity of t+1 (tb even)
      u32x2 wpair = {w0, w1};
      *(u32x2*)((char*)&xbuf[q][kh][rl] + 8 * (g & 1)) = wpair;
      asm volatile("s_waitcnt lgkmcnt(0)\n\ts_barrier" ::: "memory");
      // flat lane-major reads: byte 16*lane -> conflict-free b128
      Bv0 = xbuf[q][0][lane];
      Bv1 = xbuf[q][1][lane];
    }
    xc0 = xn0; xc1 = xn1;
  }

  // ---- epilogue: out[b] = sum_rows Why * relu(h_T) ----
  float pw = 0.0f;
#pragma unroll
  for (int r = 0; r < 4; ++r)
    pw += Why[16 * mu + 4 * g + r] * fmaxf(acc[r], 0.0f);
  pw += __shfl_xor(pw, 16, 64);
  pw += __shfl_xor(pw, 32, 64);
  if (lane < 16) partial[mu][c] = pw;
  __syncthreads();
  if (mu == 0 && lane < 16)
    out[b0 + c] = partial[0][c] + partial[1][c] + partial[2][c] + partial[3][c];
}

extern "C" void kernel_launch(void* const* d_in, const int* in_sizes, int n_in,
                              void* d_out, int out_size, void* d_ws, size_t ws_size,
                              hipStream_t stream) {
  const float* x   = (const float*)d_in[0];
  const float* Wxh = (const float*)d_in[1];
  const float* Whh = (const float*)d_in[2];
  const float* Why = (const float*)d_in[3];
  float* out = (float*)d_out;
  (void)in_sizes; (void)n_in; (void)out_size; (void)d_ws; (void)ws_size;
  rnn_scan_kernel<<<dim3(RNN_B / 16), dim3(256), 0, stream>>>(x, Wxh, Whh, Why, out);
}